// Round 20
// baseline (588.985 us; speedup 1.0000x reference)
//
#include <hip/hip_runtime.h>
#include <hip/hip_bf16.h>
#include <cstdint>

#define T_TOKENS 2048
#define HIDDEN 2048
#define INTER 1408
#define NEXP 16
#define TOPK 4
#define SINTER 2816
#define CAP 768
#define BK 32

typedef __attribute__((ext_vector_type(8))) short short8;
typedef __attribute__((ext_vector_type(8))) unsigned short ushort8;
typedef __attribute__((ext_vector_type(4))) float f32x4;

__device__ __forceinline__ float4 ld4f(const float* p) {
  return *reinterpret_cast<const float4*>(p);
}

__device__ __forceinline__ unsigned short f2bf(float v) {
  unsigned int u = __float_as_uint(v);
  unsigned int r = (u + 0x7FFFu + ((u >> 16) & 1u)) >> 16;  // RNE
  return (unsigned short)r;
}

__device__ __forceinline__ void gld16(const void* g, void* l) {
  __builtin_amdgcn_global_load_lds(
      (const __attribute__((address_space(1))) void*)g,
      (__attribute__((address_space(3))) void*)l, 16, 0, 0);
}

// ---------------- router: logits -> softmax -> top4 ----------------
__global__ __launch_bounds__(64) void router_kernel(
    const float* __restrict__ x, const float* __restrict__ wg,
    int* __restrict__ topi, float* __restrict__ topw)
{
  const int t = blockIdx.x;
  const int lane = threadIdx.x;
  float acc[NEXP];
#pragma unroll
  for (int e = 0; e < NEXP; ++e) acc[e] = 0.f;
  const float* xr = x + (size_t)t * HIDDEN;
  for (int i = lane; i < HIDDEN; i += 64) {
    float xv = xr[i];
#pragma unroll
    for (int e = 0; e < NEXP; ++e) acc[e] += xv * wg[e * HIDDEN + i];
  }
#pragma unroll
  for (int e = 0; e < NEXP; ++e) {
#pragma unroll
    for (int off = 32; off > 0; off >>= 1)
      acc[e] += __shfl_xor(acc[e], off);
  }
  float m = acc[0];
#pragma unroll
  for (int e = 1; e < NEXP; ++e) m = fmaxf(m, acc[e]);
  float p[NEXP];
  float s = 0.f;
#pragma unroll
  for (int e = 0; e < NEXP; ++e) { p[e] = expf(acc[e] - m); s += p[e]; }
  const float inv = 1.f / s;
#pragma unroll
  for (int e = 0; e < NEXP; ++e) p[e] *= inv;
  if (lane == 0) {
#pragma unroll
    for (int k = 0; k < TOPK; ++k) {
      float best = -1.f; int bi = 0;
#pragma unroll
      for (int e = 0; e < NEXP; ++e)
        if (p[e] > best) { best = p[e]; bi = e; }   // strict >: lowest idx on tie
      topi[t * TOPK + k] = bi;
      topw[t * TOPK + k] = best;  // ROUTED_SCALE = 1.0
      p[bi] = -1.f;
    }
  }
}

// ------------- stable partition: slot -> (expert,pos), exact cumsum order -------------
__global__ __launch_bounds__(1024) void partition_kernel(
    const int* __restrict__ topi, float* __restrict__ topw,
    int* __restrict__ rowtok, int* __restrict__ count)
{
  __shared__ int se[T_TOKENS * TOPK];
  for (int i = threadIdx.x; i < T_TOKENS * TOPK; i += 1024) se[i] = topi[i];
  __syncthreads();

  const int wave = threadIdx.x >> 6;
  const int lane = threadIdx.x & 63;
  const uint64_t below = (lane == 0) ? 0ull : ((~0ull) >> (64 - lane));
  int base = 0;
  for (int c = 0; c < T_TOKENS * TOPK; c += 64) {
    int ev = se[c + lane];
    uint64_t mask = __ballot(ev == wave);
    if (ev == wave) {
      int my = base + __popcll(mask & below);
      if (my < CAP) rowtok[wave * CAP + my] = c + lane;
      else          topw[c + lane] = 0.f;
    }
    base += __popcll(mask);
  }
  if (lane == 0) count[wave] = base < CAP ? base : CAP;
}

// ------------- convert x -> bf16 -------------
__global__ __launch_bounds__(256) void cvt_x_kernel(
    const float* __restrict__ x, unsigned short* __restrict__ xb)
{
  const long i = ((long)blockIdx.x * 256 + threadIdx.x) * 8;
  float4 a = ld4f(x + i), b = ld4f(x + i + 4);
  float v[8] = {a.x, a.y, a.z, a.w, b.x, b.y, b.z, b.w};
  unsigned short o[8];
#pragma unroll
  for (int j = 0; j < 8; ++j) o[j] = f2bf(v[j]);
  *(ushort8*)(xb + i) = *(ushort8*)&o[0];
}

// ------------- tcvt body (device): transpose + convert one 64x64 tile ------
// prow(n) = ((n>>4)*mul + which)*16 + (n&15).
__device__ __forceinline__ void tcvt_body(
    int bx, int by, int bz,
    const float* W0, const float* W1, unsigned short* T,
    int K, int N, long tz, int mul, int nz0, int which0, int which1,
    float (*tile)[65])
{
  const float* W; int which; long zz;
  if (bz < nz0) { W = W0; which = which0; zz = bz; }
  else          { W = W1; which = which1; zz = bz - nz0; }
  W += zz * (long)K * N;
  T += zz * tz;
  const int k0 = bx * 64, n0 = by * 64;
  const int tr = threadIdx.x >> 4;
  const int tc4 = (threadIdx.x & 15) * 4;
#pragma unroll
  for (int p = 0; p < 4; ++p) {
    int r = p * 16 + tr;
    float4 v = ld4f(W + (long)(k0 + r) * N + n0 + tc4);
    tile[r][tc4] = v.x; tile[r][tc4 + 1] = v.y;
    tile[r][tc4 + 2] = v.z; tile[r][tc4 + 3] = v.w;
  }
  __syncthreads();
  const int wn = threadIdx.x >> 3;          // 0..31
  const int wk = (threadIdx.x & 7) * 8;     // 0..56
#pragma unroll
  for (int p = 0; p < 2; ++p) {
    int n = p * 32 + wn;
    unsigned short o[8];
#pragma unroll
    for (int j = 0; j < 8; ++j) o[j] = f2bf(tile[wk + j][n]);
    const int gn = n0 + n;
    const long prow = ((long)(gn >> 4) * mul + which) * 16 + (gn & 15);
    *(ushort8*)(T + prow * K + k0 + wk) = *(ushort8*)&o[0];
  }
}

// ------------- standalone tcvt (merged two-weight form) ------
__global__ __launch_bounds__(256) void tcvt_w_kernel(
    const float* __restrict__ W0, const float* __restrict__ W1,
    unsigned short* __restrict__ T,
    int K, int N, long tz, int mul, int nz0, int which0, int which1)
{
  __shared__ float tile[64][65];
  tcvt_body(blockIdx.x, blockIdx.y, blockIdx.z, W0, W1, T, K, N, tz, mul,
            nz0, which0, which1, tile);
}

// ------------- config structs for the mega kernel -------------
struct GemmCfg {
  const unsigned short* Ag; int ldka;
  const unsigned short* Bg; long bstride;
  float* C; unsigned short* H; int ldc;
  const float* TW;
  const int* arows_g; int ashift; long aexp;
  const int* crows_g; long cexp;
  const int* cnt; int Mfix; int K; int MT; int NTn;
  int epi;    // 0: C=acc; 2: fused SwiGLU->H bf16; 3: atomic combine; 4: atomicAdd
  int nblk;
};

struct TcvtCfg {
  const float* W0; const float* W1; unsigned short* T;
  int K, N; long tz; int mul, nz0, w0, w1, KX, NY, nblk;
};

// ------------- GEMM body (PROVEN R8/R14 128x128 pipeline, runtime epi) -------------
// Per-wave: 64x64 out, acc 4x4, 8 ds_read_b128 + 16 MFMA per K-step. 3-buffer LDS.
// Depth-2 counted prefetch: iter t: vmcnt(4) [stage(t) done, issued 2 iters ago]
// -> barrier -> stage(t+2) -> ds_read -> MFMA. XOR chunk swizzle: 0 conflicts.
__device__ __forceinline__ void gemm_run(const GemmCfg& c, int bid,
                                         unsigned short* sA, unsigned short* sB)
{
  const int G = c.nblk;
  const int lin = (bid & 7) * (G >> 3) + (bid >> 3);   // bijective XCD chunk (G%8==0)
  const int mt = lin % c.MT;
  const int rest = lin / c.MT;
  const int nt = rest % c.NTn;
  const int e = rest / c.NTn;

  const int M = c.cnt ? c.cnt[e] : c.Mfix;
  if (mt * 128 >= M) return;
  const int n0 = nt * 128;

  const int tid = threadIdx.x;
  const int l = tid & 63;
  const int w = tid >> 6;
  const int wm = w >> 1;
  const int wn = w & 1;
  const int fr = l & 15;
  const int fc = l >> 4;

  const int* arows = c.arows_g ? c.arows_g + e * CAP : nullptr;
  const int* crows = c.crows_g ? c.crows_g + e * CAP : nullptr;
  const unsigned short* Bexp = c.Bg + (long)e * c.bstride;

  const int rb_s = ((l >> 3) & 1) | (((l >> 5) & 1) << 1);
  const int sch = ((l & 3) ^ rb_s) * 8;
  long aoff[2], boff[2];
#pragma unroll
  for (int j = 0; j < 2; ++j) {
    const int rloc = (w * 2 + j) * 16 + (l >> 2);
    int r = mt * 128 + rloc;
    if (r > M - 1) r = M - 1;
    const long arow = arows ? (long)(arows[r] >> c.ashift) : (c.aexp * e + r);
    aoff[j] = arow * (long)c.ldka + sch;
    boff[j] = (long)(n0 + rloc) * c.K + sch;
  }

  const int rb_r = ((fr >> 1) & 1) | (((fr >> 3) & 1) << 1);
  const int pcoff = (fc ^ rb_r) * 8;

  f32x4 acc[4][4];
#pragma unroll
  for (int i = 0; i < 4; ++i)
#pragma unroll
    for (int j = 0; j < 4; ++j) acc[i][j] = (f32x4)0.f;

  const int NT = c.K / BK;

  auto stage = [&](int buf, int kt) {
#pragma unroll
    for (int j = 0; j < 2; ++j) {
      gld16(c.Ag + aoff[j] + kt, sA + buf * (128 * BK) + (w * 2 + j) * 16 * BK);
      gld16(Bexp + boff[j] + kt, sB + buf * (128 * BK) + (w * 2 + j) * 16 * BK);
    }
  };

  stage(0, 0);
  stage(1, BK);

  int rb = 0, wb = 2;
  for (int t = 0; t < NT; ++t) {
    if (t + 1 < NT) asm volatile("s_waitcnt vmcnt(4)" ::: "memory");
    else            asm volatile("s_waitcnt vmcnt(0)" ::: "memory");
    __builtin_amdgcn_s_barrier();          // all waves' stage(t) landed; all prior
    __builtin_amdgcn_sched_barrier(0);     // reads of buf[wb] retired (pin order)

    if (t + 2 < NT) stage(wb, (t + 2) * BK);

    short8 fa[4], fb[4];
#pragma unroll
    for (int mi = 0; mi < 4; ++mi)
      fa[mi] = *(const short8*)(sA + rb * (128 * BK) + (wm * 64 + mi * 16 + fr) * BK + pcoff);
#pragma unroll
    for (int ni = 0; ni < 4; ++ni)
      fb[ni] = *(const short8*)(sB + rb * (128 * BK) + (wn * 64 + ni * 16 + fr) * BK + pcoff);
#pragma unroll
    for (int mi = 0; mi < 4; ++mi)
#pragma unroll
      for (int ni = 0; ni < 4; ++ni)
        acc[mi][ni] = __builtin_amdgcn_mfma_f32_16x16x32_bf16(fa[mi], fb[ni], acc[mi][ni], 0, 0, 0);

    rb = (rb == 2) ? 0 : rb + 1;
    wb = (wb == 2) ? 0 : wb + 1;
  }

  // epilogue: C/D layout col=lane&15, row=(lane>>4)*4+rr
#pragma unroll
  for (int mi = 0; mi < 4; ++mi)
#pragma unroll
    for (int rr = 0; rr < 4; ++rr) {
      const int r = mt * 128 + wm * 64 + mi * 16 + fc * 4 + rr;
      if (r >= M) continue;
      if (c.epi == 2) {
        const long crow = crows ? (long)crows[r] : (c.cexp * e + r);
#pragma unroll
        for (int np = 0; np < 2; ++np) {
          const float g = acc[mi][2 * np][rr];
          const float u = acc[mi][2 * np + 1][rr];
          const float h = u * (g / (1.f + __expf(-g)));   // silu(g)*u
          const int i = (n0 / 32 + wn * 2 + np) * 16 + fr;  // logical col
          c.H[crow * (long)c.ldc + i] = f2bf(h);
        }
      } else if (c.epi == 3) {
        const int slot = crows[r];
        const float wgt = c.TW[slot];
        if (wgt != 0.f) {
          const long tok = slot >> 2;
#pragma unroll
          for (int ni = 0; ni < 4; ++ni) {
            const int col = n0 + wn * 64 + ni * 16 + fr;
            atomicAdd(&c.C[tok * (long)c.ldc + col], wgt * acc[mi][ni][rr]);
          }
        }
      } else if (c.epi == 4) {
        const long crow = crows ? (long)crows[r] : (c.cexp * e + r);
#pragma unroll
        for (int ni = 0; ni < 4; ++ni) {
          const int col = n0 + wn * 64 + ni * 16 + fr;
          atomicAdd(&c.C[crow * (long)c.ldc + col], acc[mi][ni][rr]);
        }
      } else {
        const long crow = crows ? (long)crows[r] : (c.cexp * e + r);
#pragma unroll
        for (int ni = 0; ni < 4; ++ni) {
          const int col = n0 + wn * 64 + ni * 16 + fr;
          c.C[crow * (long)c.ldc + col] = acc[mi][ni][rr];
        }
      }
    }
}

// ------------- mega kernel: up to 2 GEMM segments + up to 2 tcvt tail segments ------
__global__ __launch_bounds__(256, 2)
void mega_kernel(GemmCfg g1, GemmCfg g2, TcvtCfg t1, TcvtCfg t2)
{
  __shared__ __align__(16) unsigned short sA[3][128 * BK];
  __shared__ __align__(16) unsigned short sB[3][128 * BK];

  int bid = (int)blockIdx.x;
  if (bid < g1.nblk) { gemm_run(g1, bid, &sA[0][0], &sB[0][0]); return; }
  bid -= g1.nblk;
  if (bid < g2.nblk) { gemm_run(g2, bid, &sA[0][0], &sB[0][0]); return; }
  bid -= g2.nblk;
  const TcvtCfg* tc;
  if (bid < t1.nblk) { tc = &t1; }
  else               { bid -= t1.nblk; tc = &t2; }
  const int bx = bid % tc->KX;
  const int rest = bid / tc->KX;
  const int by = rest % tc->NY;
  const int bz = rest / tc->NY;
  tcvt_body(bx, by, bz, tc->W0, tc->W1, tc->T, tc->K, tc->N, tc->tz, tc->mul,
            tc->nz0, tc->w0, tc->w1, (float(*)[65])&sA[0][0]);
}

extern "C" void kernel_launch(void* const* d_in, const int* in_sizes, int n_in,
                              void* d_out, int out_size, void* d_ws, size_t ws_size,
                              hipStream_t stream)
{
  const float* x   = (const float*)d_in[0];
  const float* wg  = (const float*)d_in[1];
  const float* w1  = (const float*)d_in[2];
  const float* w3  = (const float*)d_in[3];
  const float* w2  = (const float*)d_in[4];
  const float* ws1 = (const float*)d_in[5];
  const float* ws3 = (const float*)d_in[6];
  const float* ws2 = (const float*)d_in[7];
  float* out = (float*)d_out;

  char* w = (char*)d_ws;
  int*   topi   = (int*)w;   w += (size_t)T_TOKENS * TOPK * 4;
  float* topw   = (float*)w; w += (size_t)T_TOKENS * TOPK * 4;
  int*   rowtok = (int*)w;   w += (size_t)NEXP * CAP * 4;
  int*   count  = (int*)w;   w += 256;
  uintptr_t a = (uintptr_t)w; a = (a + 255) & ~(uintptr_t)255; w = (char*)a;

  const size_t XSZ  = (size_t)T_TOKENS * HIDDEN;            // 4.19M
  const size_t WSI  = (size_t)2 * HIDDEN * SINTER;          // 11.5M  (interleaved ws1/ws3)
  const size_t WRI  = (size_t)2 * NEXP * HIDDEN * INTER;    // 92.3M  (interleaved w1/w3)
  const size_t WR2  = (size_t)NEXP * INTER * HIDDEN;        // 46.1M  (w2T, own buffer)
  const size_t HSSZ = (size_t)T_TOKENS * SINTER;            // 5.77M
  const size_t HRSZ = (size_t)NEXP * CAP * INTER;           // 17.3M

  unsigned short* xb  = (unsigned short*)w; w += XSZ * 2;   // 8.4 MB
  unsigned short* wSi = (unsigned short*)w; w += WSI * 2;   // 23.1 MB; reused as ws2T
  unsigned short* wRi = (unsigned short*)w; w += WRI * 2;   // 184.5 MB
  unsigned short* wR2 = (unsigned short*)w; w += WR2 * 2;   // 92.3 MB (separate: no alias!)
  unsigned short* hs  = (unsigned short*)w; w += HSSZ * 2;  // 11.5 MB
  unsigned short* hr  = (unsigned short*)w; w += HRSZ * 2;  // 34.6 MB
  unsigned short* wS2 = wSi;   // ws2T aliases wSi (safe: wSi's last reader is L2)

  // out accumulates atomically from both down-GEMMs: zero it first.
  hipMemsetAsync(out, 0, (size_t)T_TOKENS * HIDDEN * 4, stream);

  router_kernel<<<T_TOKENS, 64, 0, stream>>>(x, wg, topi, topw);
  partition_kernel<<<1, 1024, 0, stream>>>(topi, topw, rowtok, count);
  cvt_x_kernel<<<(int)(XSZ / (256 * 8)), 256, 0, stream>>>(x, xb);

  GemmCfg gz = {}; TcvtCfg tz = {};

  // ---- L1: tcvt shared ws1/ws3 (standalone; first in chain) ----
  tcvt_w_kernel<<<dim3(HIDDEN / 64, SINTER / 64, 2), 256, 0, stream>>>(
      ws1, ws3, wSi, HIDDEN, SINTER, 0L, 2, 1, 0, 1);

  // ---- L2: shared upgate GEMM (704) ∥ tcvt routed w1/w3 (22528) ----
  {
    GemmCfg g1 = { xb, HIDDEN, wSi, 0L, nullptr, hs, SINTER, nullptr,
                   nullptr, 0, 0L, nullptr, 0L,
                   nullptr, T_TOKENS, HIDDEN, T_TOKENS / 128, 2 * SINTER / 128,
                   2, (T_TOKENS / 128) * (2 * SINTER / 128) };
    TcvtCfg t1 = { w1, w3, wRi, HIDDEN, INTER, (long)2 * HIDDEN * INTER,
                   2, NEXP, 0, 1, HIDDEN / 64, INTER / 64,
                   (HIDDEN / 64) * (INTER / 64) * (2 * NEXP) };
    mega_kernel<<<g1.nblk + t1.nblk, 256, 0, stream>>>(g1, gz, t1, tz);
  }

  // ---- L3: routed upgate GEMM (2112) ∥ tcvt ws2 (1408) ∥ tcvt w2 -> wR2 (11264) ----
  // (wR2 is a SEPARATE buffer: no alias with wRi, which g1 reads concurrently)
  {
    GemmCfg g1 = { xb, HIDDEN, wRi, (long)2 * HIDDEN * INTER, nullptr, hr, INTER, nullptr,
                   rowtok, 2, 0L, nullptr, (long)CAP,
                   count, 0, HIDDEN, CAP / 128, 2 * INTER / 128,
                   2, (CAP / 128) * (2 * INTER / 128) * NEXP };
    TcvtCfg t1 = { ws2, ws2, wS2, SINTER, HIDDEN, 0L,
                   1, 1, 0, 0, SINTER / 64, HIDDEN / 64,
                   (SINTER / 64) * (HIDDEN / 64) };
    TcvtCfg t2 = { w2, w2, wR2, INTER, HIDDEN, (long)INTER * HIDDEN,
                   1, NEXP, 0, 0, INTER / 64, HIDDEN / 64,
                   (INTER / 64) * (HIDDEN / 64) * NEXP };
    mega_kernel<<<g1.nblk + t1.nblk + t2.nblk, 256, 0, stream>>>(g1, gz, t1, t2);
  }

  // ---- L45: shared down (atomic, 256) + routed down fused combine (1536) ----
  {
    GemmCfg g1 = { hs, SINTER, wS2, 0L, out, nullptr, HIDDEN, nullptr,
                   nullptr, 0, 0L, nullptr, 0L,
                   nullptr, T_TOKENS, SINTER, T_TOKENS / 128, HIDDEN / 128,
                   4, (T_TOKENS / 128) * (HIDDEN / 128) };
    GemmCfg g2 = { hr, INTER, wR2, (long)INTER * HIDDEN, out, nullptr, HIDDEN, topw,
                   nullptr, 0, (long)CAP, rowtok, 0L,
                   count, 0, INTER, CAP / 128, HIDDEN / 128,
                   3, (CAP / 128) * (HIDDEN / 128) * NEXP };
    mega_kernel<<<g1.nblk + g2.nblk, 256, 0, stream>>>(g1, g2, tz, tz);
  }
}